// Round 14
// baseline (4857.013 us; speedup 1.0000x reference)
//
#include <hip/hip_runtime.h>

#define H 512
#define NB 256
#define OBS 128
#define LSTEPS 512
#define TB 8                      // timesteps per phase
#define NTB (LSTEPS / TB)         // 64 timestep-blocks
#define NPHASE (NTB + 8)          // 72 phases (lag-2 wavefront)
#define NWG 256
#define NTHR 512
#define WROWS 513                 // 512 weight rows + zero row
#define PLANE (NB * H)
#define MPLANE ((size_t)TB * NB * 8)   // u64 per mask plane
typedef unsigned long long u64;

// fc_Wt[l][k][h] = fc_W[l][h][k], row 512 = 0;  enc_Wt[k][h] = enc_W[h][k]
__global__ __launch_bounds__(256) void prep_weights(const float* __restrict__ enc_W,
                                                    const float* __restrict__ fc_W,
                                                    float* __restrict__ enc_Wt,
                                                    float* __restrict__ fc_Wt) {
    int idx = blockIdx.x * 256 + threadIdx.x;
    int stride = gridDim.x * 256;
    for (int i = idx; i < 4 * WROWS * H; i += stride) {
        int l = i / (WROWS * H);
        int r = (i / H) % WROWS;
        int h = i & 511;
        fc_Wt[i] = (r < 512) ? fc_W[l * H * H + h * H + r] : 0.0f;
    }
    for (int i = idx; i < OBS * H; i += stride) {
        int k = i >> 9;
        int h = i & 511;
        enc_Wt[i] = enc_W[h * OBS + k];
    }
}

__device__ __forceinline__ u64 spread2(unsigned int v) {   // bit i -> bit 2i
    u64 z = v;
    z = (z | (z << 16)) & 0x0000FFFF0000FFFFull;
    z = (z | (z << 8))  & 0x00FF00FF00FF00FFull;
    z = (z | (z << 4))  & 0x0F0F0F0F0F0F0F0Full;
    z = (z | (z << 2))  & 0x3333333333333333ull;
    z = (z | (z << 1))  & 0x5555555555555555ull;
    return z;
}
__device__ __forceinline__ u64 spread4(unsigned int v) {   // bit i -> bit 4i (16-bit in)
    u64 z = v & 0xFFFFull;
    z = (z | (z << 24)) & 0x000000FF000000FFull;
    z = (z | (z << 12)) & 0x000F000F000F000Full;
    z = (z | (z << 6))  & 0x0303030303030303ull;
    z = (z | (z << 3))  & 0x1111111111111111ull;
    return z;
}

__global__ __launch_bounds__(NTHR, 2) void snn_persistent(
    const float* __restrict__ x,        // [512][256][128]
    const float* __restrict__ mem0,     // [5][256][512]
    const float* __restrict__ enc_b,    // [512]
    const float* __restrict__ fc_b,     // [4][512]
    const float* __restrict__ enc_Wt,   // [128][512] k-major
    const float* __restrict__ fc_Wt,    // [4][513][512] k-major, row 512 = 0
    u64* __restrict__ masks,            // [4 cons][4 plane][TB][256 n][8 w]
    int* __restrict__ bar,              // slots[256] | done[32] | rel[256]
    float* __restrict__ out)            // [512][256][512] spikes + [5][256][512] mem
{
    __shared__ float Wsh[513][64];      // 128.25 KB persistent weights + zero row
    __shared__ u64  Msh[TB][32][8];     // 16 KB staged masks

    const int tid = threadIdx.x;
    const int wg  = blockIdx.x;
    const int wave = tid >> 6;          // 0..7
    const int lane = tid & 63;

    // fc role: layer, 64-h slice, 32-n group; wave owns 4 n rows
    const int layer = wg >> 6;
    const int hs = (wg >> 3) & 7;
    const int g  = wg & 7;
    const int h0 = hs << 6;
    const int n0 = g << 5;
    const int ng = lane >> 4;           // 0..3 (row group)
    const int hq = lane & 15;
    const int hq4 = hq << 2;
    const int nl = (wave << 2) | ng;    // 0..31

    // enc role (waves 0..3 only)
    const int ew  = wg >> 5;            // h-word 0..7
    const int eh0 = ew << 6;
    const int en0 = (wg & 31) << 3;
    const int enl = 2 * wave + (lane >> 5);
    const int en  = en0 + enl;
    const int hp  = lane & 31;
    const int eh  = eh0 + 2 * hp;

    // barrier roles
    int* slots = bar;
    int* done  = bar + 256;
    int* rel   = bar + 288;
    const int grp = wg & 7;
    const int gidx = wg >> 3;

    // ---------- one-time W staging ----------
    const float* Wl = fc_Wt + (size_t)layer * (WROWS * H);
    #pragma unroll
    for (int i = 0; i < 16; ++i) {
        int id = tid + NTHR * i;        // 8192 float4
        int row = id >> 4, c4 = id & 15;
        *(float4*)&Wsh[row][c4 * 4] = *(const float4*)(Wl + (size_t)row * H + h0 + c4 * 4);
    }
    if (tid < 64) Wsh[512][tid] = 0.f;  // zero row for +0.0 pads

    const float* WgL = Wl + h0 + hq4;   // global W source (L2), per-lane column; row 512 = 0

    const float4 bfc = *(const float4*)(fc_b + layer * H + h0 + hq4);
    float4 mem_fc = *(const float4*)(mem0 + (size_t)(layer + 1) * PLANE +
                                     (size_t)(n0 + nl) * H + h0 + hq4);
    float2 be2 = make_float2(0.f, 0.f);
    float2 mem_e = make_float2(0.f, 0.f);
    if (wave < 4) {
        be2   = *(const float2*)(enc_b + eh);
        mem_e = *(const float2*)(mem0 + (size_t)en * H + eh);
    }

    const bool oddw = (wave & 1) != 0;

    __syncthreads();

    // ---------- phase loop (lag-2 wavefront) ----------
    for (int p = 0; p < NPHASE; ++p) {
        const int  tb_fc  = p - 2 - 2 * layer;
        const bool fc_act = (tb_fc >= 0) && (tb_fc < NTB);
        const bool enc_act = (p < NTB);

        // ---- top wait: everyone finished phase p-2 ----
        if (tid == 0 && p >= 2) {
            while (__hip_atomic_load(rel + grp * 32,
                                     __ATOMIC_RELAXED, __HIP_MEMORY_SCOPE_AGENT) < p - 1)
                __builtin_amdgcn_s_sleep(1);
        }
        __syncthreads();

        // ---- stage masks into LDS ----
        if (fc_act) {
            const u64* msrc = masks + ((size_t)layer * 4 + ((p + 2) & 3)) * MPLANE;
            #pragma unroll
            for (int i = 0; i < 4; ++i) {
                int id = tid + NTHR * i;        // 2048 u64
                int tt = id >> 8, n_l = (id >> 3) & 31, w = id & 7;
                u64 v = __hip_atomic_load(msrc + ((size_t)tt * NB + n0 + n_l) * 8 + w,
                                          __ATOMIC_RELAXED, __HIP_MEMORY_SCOPE_AGENT);
                Msh[tt][n_l][w] = v;
            }
        }
        __syncthreads();

        // ---- encoder (waves 0..3; waves 4..7 fall through to gather) ----
        if (enc_act && wave < 4) {
            float2 ea[TB];
            #pragma unroll
            for (int tt = 0; tt < TB; ++tt) ea[tt] = make_float2(0.f, 0.f);
            const float* xbase = x + (size_t)(TB * p) * NB * OBS + (size_t)en * OBS;
            for (int k2 = 0; k2 < 64; ++k2) {
                float2 w0 = *(const float2*)(enc_Wt + (size_t)(2 * k2) * H + eh);
                float2 w1 = *(const float2*)(enc_Wt + (size_t)(2 * k2 + 1) * H + eh);
                #pragma unroll
                for (int tt = 0; tt < TB; ++tt) {
                    float2 xv = *(const float2*)(xbase + (size_t)tt * NB * OBS + 2 * k2);
                    ea[tt].x += xv.x * w0.x; ea[tt].y += xv.x * w0.y;
                    ea[tt].x += xv.y * w1.x; ea[tt].y += xv.y * w1.y;
                }
            }
            u64* edst = masks + (size_t)(0 * 4 + (p & 3)) * MPLANE;   // consumer layer 0
            #pragma unroll
            for (int tt = 0; tt < TB; ++tt) {
                float m0, m1;
                {
                    float inp = ea[tt].x + be2.x; float mp = mem_e.x;
                    float reset = (mp > 1.0f) ? 1.0f : 0.0f;
                    m0 = 0.9f * mp + inp - reset; mem_e.x = m0;
                }
                {
                    float inp = ea[tt].y + be2.y; float mp = mem_e.y;
                    float reset = (mp > 1.0f) ? 1.0f : 0.0f;
                    m1 = 0.9f * mp + inp - reset; mem_e.y = m1;
                }
                u64 b0 = __ballot(m0 > 1.0f);
                u64 b1 = __ballot(m1 > 1.0f);
                unsigned int s0 = (unsigned int)(b0 >> (lane & 32));
                unsigned int s1 = (unsigned int)(b1 >> (lane & 32));
                u64 word = spread2(s0) | (spread2(s1) << 1);
                if ((lane & 31) == 0)
                    __hip_atomic_store(edst + ((size_t)tt * NB + en) * 8 + ew, word,
                                       __ATOMIC_RELAXED, __HIP_MEMORY_SCOPE_AGENT);
            }
        }

        // ---- fc sparse gather x TB (bit-exact: ascending k, +0 identities)
        //      per-(wave,tt) source: LDS or global/L2 chunk-8; staggered by parity ----
        if (fc_act) {
            float* outp = out + (size_t)(TB * tb_fc) * PLANE;
            u64* mdst = masks + ((size_t)(layer + 1) * 4 + (p & 3)) * MPLANE;

            #define LIF_PACK(TT, MNEW)                                                     \
            {                                                                              \
                if (layer < 3) {                                                           \
                    u64 B0 = __ballot(MNEW.x > 1.0f);                                      \
                    u64 B1 = __ballot(MNEW.y > 1.0f);                                      \
                    u64 B2 = __ballot(MNEW.z > 1.0f);                                      \
                    u64 B3 = __ballot(MNEW.w > 1.0f);                                      \
                    const int sh = ng << 4;                                                \
                    u64 word = spread4((unsigned int)(B0 >> sh))                           \
                             | (spread4((unsigned int)(B1 >> sh)) << 1)                    \
                             | (spread4((unsigned int)(B2 >> sh)) << 2)                    \
                             | (spread4((unsigned int)(B3 >> sh)) << 3);                   \
                    if (hq == 0)                                                           \
                        __hip_atomic_store(mdst + ((size_t)(TT) * NB + n0 + nl) * 8 + hs,  \
                                           word, __ATOMIC_RELAXED, __HIP_MEMORY_SCOPE_AGENT); \
                } else {                                                                   \
                    float4 s4;                                                             \
                    s4.x = (MNEW.x > 1.0f) ? 1.0f : 0.0f;                                  \
                    s4.y = (MNEW.y > 1.0f) ? 1.0f : 0.0f;                                  \
                    s4.z = (MNEW.z > 1.0f) ? 1.0f : 0.0f;                                  \
                    s4.w = (MNEW.w > 1.0f) ? 1.0f : 0.0f;                                  \
                    *(float4*)(outp + (size_t)(TT) * PLANE +                               \
                               (size_t)(n0 + nl) * H + h0 + hq4) = s4;                     \
                }                                                                          \
            }

            #define LIF_STEP(ACC, MNEW)                                                    \
                { float inp = ACC.x + bfc.x; float mp = mem_fc.x;                          \
                  float reset = (mp > 1.0f) ? 1.0f : 0.0f; MNEW.x = 0.9f * mp + inp - reset; } \
                { float inp = ACC.y + bfc.y; float mp = mem_fc.y;                          \
                  float reset = (mp > 1.0f) ? 1.0f : 0.0f; MNEW.y = 0.9f * mp + inp - reset; } \
                { float inp = ACC.z + bfc.z; float mp = mem_fc.z;                          \
                  float reset = (mp > 1.0f) ? 1.0f : 0.0f; MNEW.z = 0.9f * mp + inp - reset; } \
                { float inp = ACC.w + bfc.w; float mp = mem_fc.w;                          \
                  float reset = (mp > 1.0f) ? 1.0f : 0.0f; MNEW.w = 0.9f * mp + inp - reset; } \
                mem_fc = MNEW;

            // LDS-sourced chain (R11 depth-2 pair pipeline)
            #define GATHER_L(TT)                                                           \
            {                                                                              \
                float4 acc = make_float4(0.f, 0.f, 0.f, 0.f);                              \
                _Pragma("unroll 1")                                                        \
                for (int w = 0; w < 8; ++w) {                                              \
                    u64 rem = Msh[TT][nl][w];                                              \
                    if (!__any((int)(rem != 0ull))) continue;                              \
                    const int kb = w << 6;                                                 \
                    const int pop = __popcll(rem);                                         \
                    if (pop) {                                                             \
                        const int nit = (pop + 1) >> 1;                                    \
                        int b0 = kb + __builtin_ctzll(rem); rem &= rem - 1;                \
                        int b1 = rem ? kb + __builtin_ctzll(rem) : 512; rem &= rem - 1;    \
                        float4 w0 = *(const float4*)&Wsh[b0][hq4];                         \
                        float4 w1 = make_float4(0.f, 0.f, 0.f, 0.f);                       \
                        if (b1 < 512) w1 = *(const float4*)&Wsh[b1][hq4];                  \
                        _Pragma("unroll 1")                                                \
                        for (int i = 1; i < nit; ++i) {                                    \
                            int c0 = kb + __builtin_ctzll(rem); rem &= rem - 1;            \
                            int c1 = rem ? kb + __builtin_ctzll(rem) : 512; rem &= rem - 1;\
                            float4 u0 = *(const float4*)&Wsh[c0][hq4];                     \
                            float4 u1 = make_float4(0.f, 0.f, 0.f, 0.f);                   \
                            if (c1 < 512) u1 = *(const float4*)&Wsh[c1][hq4];              \
                            acc.x += w0.x; acc.y += w0.y; acc.z += w0.z; acc.w += w0.w;    \
                            acc.x += w1.x; acc.y += w1.y; acc.z += w1.z; acc.w += w1.w;    \
                            w0 = u0; w1 = u1;                                              \
                        }                                                                  \
                        acc.x += w0.x; acc.y += w0.y; acc.z += w0.z; acc.w += w0.w;        \
                        acc.x += w1.x; acc.y += w1.y; acc.z += w1.z; acc.w += w1.w;        \
                    }                                                                      \
                }                                                                          \
                float4 mnew;                                                               \
                LIF_STEP(acc, mnew)                                                        \
                LIF_PACK(TT, mnew)                                                         \
            }

            // global/L2-sourced chain, 8-deep prefetch chunks; pads hit zero row 512
            #define GATHER_G(TT)                                                           \
            {                                                                              \
                float4 acc = make_float4(0.f, 0.f, 0.f, 0.f);                              \
                _Pragma("unroll 1")                                                        \
                for (int w = 0; w < 8; ++w) {                                              \
                    u64 rem = Msh[TT][nl][w];                                              \
                    const int kb = w << 6;                                                 \
                    while (__any((int)(rem != 0ull))) {                                    \
                        int i0 = rem ? kb + __builtin_ctzll(rem) : 512; rem &= rem - 1;    \
                        int i1 = rem ? kb + __builtin_ctzll(rem) : 512; rem &= rem - 1;    \
                        int i2 = rem ? kb + __builtin_ctzll(rem) : 512; rem &= rem - 1;    \
                        int i3 = rem ? kb + __builtin_ctzll(rem) : 512; rem &= rem - 1;    \
                        int i4 = rem ? kb + __builtin_ctzll(rem) : 512; rem &= rem - 1;    \
                        int i5 = rem ? kb + __builtin_ctzll(rem) : 512; rem &= rem - 1;    \
                        int i6 = rem ? kb + __builtin_ctzll(rem) : 512; rem &= rem - 1;    \
                        int i7 = rem ? kb + __builtin_ctzll(rem) : 512; rem &= rem - 1;    \
                        float4 v0 = *(const float4*)(WgL + (size_t)i0 * H);                \
                        float4 v1 = *(const float4*)(WgL + (size_t)i1 * H);                \
                        float4 v2 = *(const float4*)(WgL + (size_t)i2 * H);                \
                        float4 v3 = *(const float4*)(WgL + (size_t)i3 * H);                \
                        float4 v4 = *(const float4*)(WgL + (size_t)i4 * H);                \
                        float4 v5 = *(const float4*)(WgL + (size_t)i5 * H);                \
                        float4 v6 = *(const float4*)(WgL + (size_t)i6 * H);                \
                        float4 v7 = *(const float4*)(WgL + (size_t)i7 * H);                \
                        acc.x += v0.x; acc.y += v0.y; acc.z += v0.z; acc.w += v0.w;        \
                        acc.x += v1.x; acc.y += v1.y; acc.z += v1.z; acc.w += v1.w;        \
                        acc.x += v2.x; acc.y += v2.y; acc.z += v2.z; acc.w += v2.w;        \
                        acc.x += v3.x; acc.y += v3.y; acc.z += v3.z; acc.w += v3.w;        \
                        acc.x += v4.x; acc.y += v4.y; acc.z += v4.z; acc.w += v4.w;        \
                        acc.x += v5.x; acc.y += v5.y; acc.z += v5.z; acc.w += v5.w;        \
                        acc.x += v6.x; acc.y += v6.y; acc.z += v6.z; acc.w += v6.w;        \
                        acc.x += v7.x; acc.y += v7.y; acc.z += v7.z; acc.w += v7.w;        \
                    }                                                                      \
                }                                                                          \
                float4 mnew;                                                               \
                LIF_STEP(acc, mnew)                                                        \
                LIF_PACK(TT, mnew)                                                         \
            }

            // staggered source map (wave-uniform branches; LIF order 0..7 preserved)
            if (oddw) { GATHER_G(0) } else { GATHER_L(0) }
            if (oddw) { GATHER_G(1) } else { GATHER_L(1) }
            if (oddw) { GATHER_G(2) } else { GATHER_L(2) }
            GATHER_L(3)
            GATHER_L(4)
            if (oddw) { GATHER_L(5) } else { GATHER_G(5) }
            if (oddw) { GATHER_L(6) } else { GATHER_G(6) }
            if (oddw) { GATHER_L(7) } else { GATHER_G(7) }

            #undef GATHER_L
            #undef GATHER_G
            #undef LIF_STEP
            #undef LIF_PACK
        }

        // ---- arrive B_p, then deferred completion of B_{p-1} ----
        asm volatile("s_waitcnt vmcnt(0)" ::: "memory");
        __syncthreads();
        if (tid == 0) {
            __hip_atomic_store(slots + grp * 32 + gidx, p + 1,
                               __ATOMIC_RELAXED, __HIP_MEMORY_SCOPE_AGENT);
            if (gidx == 0 && p >= 1) {
                const int target = p;
                for (;;) {
                    int all = 1;
                    #pragma unroll
                    for (int i = 0; i < 32; ++i) {
                        int v = __hip_atomic_load(slots + grp * 32 + i,
                                                  __ATOMIC_RELAXED, __HIP_MEMORY_SCOPE_AGENT);
                        all &= (v >= target);
                    }
                    if (all) break;
                }
                __hip_atomic_store(done + grp, target,
                                   __ATOMIC_RELAXED, __HIP_MEMORY_SCOPE_AGENT);
                for (;;) {
                    int all = 1;
                    #pragma unroll
                    for (int i = 0; i < 8; ++i) {
                        int v = __hip_atomic_load(done + i,
                                                  __ATOMIC_RELAXED, __HIP_MEMORY_SCOPE_AGENT);
                        all &= (v >= target);
                    }
                    if (all) break;
                }
                __hip_atomic_store(rel + grp * 32, target,
                                   __ATOMIC_RELAXED, __HIP_MEMORY_SCOPE_AGENT);
            }
        }
        // no trailing syncthreads: next phase's top-wait + syncthreads re-converges
    }

    // ---------- final membrane state ----------
    float* outm = out + (size_t)LSTEPS * PLANE;
    if (wave < 4)
        *(float2*)(outm + (size_t)en * H + eh) = mem_e;
    *(float4*)(outm + (size_t)(layer + 1) * PLANE + (size_t)(n0 + nl) * H + h0 + hq4) = mem_fc;
}

extern "C" void kernel_launch(void* const* d_in, const int* in_sizes, int n_in,
                              void* d_out, int out_size, void* d_ws, size_t ws_size,
                              hipStream_t stream) {
    const float* x     = (const float*)d_in[0];
    const float* mem0  = (const float*)d_in[1];
    const float* enc_W = (const float*)d_in[2];
    const float* enc_b = (const float*)d_in[3];
    const float* fc_W  = (const float*)d_in[4];
    const float* fc_b  = (const float*)d_in[5];
    float* out = (float*)d_out;

    float* fc_Wt  = (float*)d_ws;                     // 4*513*512 f32 ≈ 4.1 MB
    float* enc_Wt = fc_Wt + 4 * WROWS * H;            // 256 KB
    u64*   masks  = (u64*)(enc_Wt + OBS * H);         // 16 planes * 16384 u64 = 2 MB
    int*   bar    = (int*)(masks + 16 * MPLANE);      // slots 256 | done 32 | rel 256

    hipMemsetAsync(bar, 0, 544 * sizeof(int), stream);
    prep_weights<<<dim3(512), dim3(256), 0, stream>>>(enc_W, fc_W, enc_Wt, fc_Wt);
    snn_persistent<<<dim3(NWG), dim3(NTHR), 0, stream>>>(
        x, mem0, enc_b, fc_b, enc_Wt, fc_Wt, masks, bar, out);
}

// Round 15
// 3802.515 us; speedup vs baseline: 1.2773x; 1.2773x over previous
//
#include <hip/hip_runtime.h>

#define H 512
#define NB 256
#define OBS 128
#define LSTEPS 512
#define TB 8                      // timesteps per phase
#define NTB (LSTEPS / TB)         // 64 timestep-blocks
#define NPHASE (NTB + 4)          // 68 phases
#define NWG 256
#define NTHR 512
#define PLANE (NB * H)
#define PLSZ ((size_t)TB * NB * 8)   // u64 per mask plane
typedef unsigned long long u64;

// fc_Wt[l][k][h] = fc_W[l][h][k];  enc_Wt[k][h] = enc_W[h][k]
__global__ __launch_bounds__(256) void prep_weights(const float* __restrict__ enc_W,
                                                    const float* __restrict__ fc_W,
                                                    float* __restrict__ enc_Wt,
                                                    float* __restrict__ fc_Wt) {
    int idx = blockIdx.x * 256 + threadIdx.x;
    int stride = gridDim.x * 256;
    for (int i = idx; i < 4 * H * H; i += stride) {
        int l = i >> 18;
        int k = (i >> 9) & 511;
        int h = i & 511;
        fc_Wt[i] = fc_W[l * H * H + h * H + k];
    }
    for (int i = idx; i < OBS * H; i += stride) {
        int k = i >> 9;
        int h = i & 511;
        enc_Wt[i] = enc_W[h * OBS + k];
    }
}

__device__ __forceinline__ u64 spread2(unsigned int v) {   // bit i -> bit 2i
    u64 z = v;
    z = (z | (z << 16)) & 0x0000FFFF0000FFFFull;
    z = (z | (z << 8))  & 0x00FF00FF00FF00FFull;
    z = (z | (z << 4))  & 0x0F0F0F0F0F0F0F0Full;
    z = (z | (z << 2))  & 0x3333333333333333ull;
    z = (z | (z << 1))  & 0x5555555555555555ull;
    return z;
}
__device__ __forceinline__ u64 spread4(unsigned int v) {   // bit i -> bit 4i (16-bit in)
    u64 z = v & 0xFFFFull;
    z = (z | (z << 24)) & 0x000000FF000000FFull;
    z = (z | (z << 12)) & 0x000F000F000F000Full;
    z = (z | (z << 6))  & 0x0303030303030303ull;
    z = (z | (z << 3))  & 0x1111111111111111ull;
    return z;
}

__global__ __launch_bounds__(NTHR, 2) void snn_persistent(
    const float* __restrict__ x,        // [512][256][128]
    const float* __restrict__ mem0,     // [5][256][512]
    const float* __restrict__ enc_b,    // [512]
    const float* __restrict__ fc_b,     // [4][512]
    const float* __restrict__ enc_Wt,   // [128][512] k-major
    const float* __restrict__ fc_Wt,    // [4][512][512] k-major
    u64* __restrict__ masks,            // [4 cons][2 parity][TB][256 n][8 w]
    int* __restrict__ bar,              // slots[256] | done[32] | rel[256]
    float* __restrict__ out)            // [512][256][512] spikes + [5][256][512] mem
{
    __shared__ float Wsh[513][64];      // 128.25 KB persistent weights + zero row
    __shared__ u64  Msh[TB][32][8];     // 16 KB staged masks

    const int tid = threadIdx.x;
    const int wg  = blockIdx.x;
    const int wave = tid >> 6;          // 0..7
    const int lane = tid & 63;

    // fc role: layer, 64-h slice, 32-n group; wave owns 4 n rows
    const int layer = wg >> 6;
    const int hs = (wg >> 3) & 7;
    const int g  = wg & 7;
    const int h0 = hs << 6;
    const int n0 = g << 5;
    const int ng = lane >> 4;           // 0..3 (row group)
    const int hq = lane & 15;
    const int hq4 = hq << 2;
    const int nl = (wave << 2) | ng;    // 0..31

    // enc role (waves 0..3 only): 8 n x 64 h sliver, thread = (1 n, 2 h)
    const int ew  = wg >> 5;            // h-word 0..7
    const int eh0 = ew << 6;
    const int en0 = (wg & 31) << 3;
    const int enl = 2 * wave + (lane >> 5);   // 0..7 (valid when wave<4)
    const int en  = en0 + enl;
    const int hp  = lane & 31;
    const int eh  = eh0 + 2 * hp;

    // barrier roles
    int* slots = bar;
    int* done  = bar + 256;
    int* rel   = bar + 288;
    const int grp = wg & 7;
    const int gidx = wg >> 3;

    // ---------- one-time W staging ----------
    const float* Wl = fc_Wt + (size_t)layer * H * H;
    #pragma unroll
    for (int i = 0; i < 16; ++i) {
        int id = tid + NTHR * i;        // 8192 float4
        int row = id >> 4, c4 = id & 15;
        *(float4*)&Wsh[row][c4 * 4] = *(const float4*)(Wl + (size_t)row * H + h0 + c4 * 4);
    }
    if (tid < 64) Wsh[512][tid] = 0.f;  // zero row for +0.0 pads

    const float4 bfc = *(const float4*)(fc_b + layer * H + h0 + hq4);
    float4 mem_fc = *(const float4*)(mem0 + (size_t)(layer + 1) * PLANE +
                                     (size_t)(n0 + nl) * H + h0 + hq4);
    float2 be2 = make_float2(0.f, 0.f);
    float2 mem_e = make_float2(0.f, 0.f);
    if (wave < 4) {
        be2   = *(const float2*)(enc_b + eh);
        mem_e = *(const float2*)(mem0 + (size_t)en * H + eh);
    }

    __syncthreads();

    // ---------- phase loop ----------
    for (int p = 0; p < NPHASE; ++p) {
        const int  tb_fc  = p - 1 - layer;
        const bool fc_act = (tb_fc >= 0) && (tb_fc < NTB);
        const bool enc_act = (p < NTB);

        // ---- stage masks into LDS (L3-coherent loads) ----
        if (fc_act) {
            const u64* msrc = masks + (size_t)(layer * 2 + ((p + 1) & 1)) * PLSZ;
            #pragma unroll
            for (int i = 0; i < 4; ++i) {
                int id = tid + NTHR * i;        // 2048 u64
                int tt = id >> 8, n_l = (id >> 3) & 31, w = id & 7;
                u64 v = __hip_atomic_load(msrc + ((size_t)tt * NB + n0 + n_l) * 8 + w,
                                          __ATOMIC_RELAXED, __HIP_MEMORY_SCOPE_AGENT);
                Msh[tt][n_l][w] = v;
            }
        }
        __syncthreads();

        // ---- encoder (waves 0..3; waves 4..7 fall through to gather) ----
        if (enc_act && wave < 4) {
            float2 ea[TB];
            #pragma unroll
            for (int tt = 0; tt < TB; ++tt) ea[tt] = make_float2(0.f, 0.f);
            const float* xbase = x + (size_t)(TB * p) * NB * OBS + (size_t)en * OBS;
            for (int k2 = 0; k2 < 64; ++k2) {
                float2 w0 = *(const float2*)(enc_Wt + (size_t)(2 * k2) * H + eh);
                float2 w1 = *(const float2*)(enc_Wt + (size_t)(2 * k2 + 1) * H + eh);
                #pragma unroll
                for (int tt = 0; tt < TB; ++tt) {
                    float2 xv = *(const float2*)(xbase + (size_t)tt * NB * OBS + 2 * k2);
                    ea[tt].x += xv.x * w0.x; ea[tt].y += xv.x * w0.y;
                    ea[tt].x += xv.y * w1.x; ea[tt].y += xv.y * w1.y;
                }
            }
            u64* edst = masks + (size_t)(p & 1) * PLSZ;   // consumer layer 0
            #pragma unroll
            for (int tt = 0; tt < TB; ++tt) {
                float m0, m1;
                {
                    float inp = ea[tt].x + be2.x; float mp = mem_e.x;
                    float reset = (mp > 1.0f) ? 1.0f : 0.0f;
                    m0 = 0.9f * mp + inp - reset; mem_e.x = m0;
                }
                {
                    float inp = ea[tt].y + be2.y; float mp = mem_e.y;
                    float reset = (mp > 1.0f) ? 1.0f : 0.0f;
                    m1 = 0.9f * mp + inp - reset; mem_e.y = m1;
                }
                u64 b0 = __ballot(m0 > 1.0f);
                u64 b1 = __ballot(m1 > 1.0f);
                unsigned int s0 = (unsigned int)(b0 >> (lane & 32));
                unsigned int s1 = (unsigned int)(b1 >> (lane & 32));
                u64 word = spread2(s0) | (spread2(s1) << 1);
                if ((lane & 31) == 0)
                    __hip_atomic_store(edst + ((size_t)tt * NB + en) * 8 + ew, word,
                                       __ATOMIC_RELAXED, __HIP_MEMORY_SCOPE_AGENT);
            }
        }

        // ---- fc sparse gather x TB (bit-exact: ascending k, +0 pads) ----
        if (fc_act) {
            float* outp = out + (size_t)(TB * tb_fc) * PLANE;
            u64* mdst = masks + (size_t)((layer + 1) * 2 + (p & 1)) * PLSZ;
            #pragma unroll 1
            for (int tt = 0; tt < TB; ++tt) {
                float4 acc = make_float4(0.f, 0.f, 0.f, 0.f);
                #pragma unroll 1
                for (int w = 0; w < 8; ++w) {
                    u64 rem = Msh[tt][nl][w];
                    int pop = __popcll(rem);
                    int mx = max(pop, __shfl_xor(pop, 16, 64));
                    mx = max(mx, __shfl_xor(mx, 32, 64));
                    if (mx == 0) continue;           // wave-uniform skip
                    const int kb = w << 6;
                    const int nit = (mx + 1) >> 1;
                    int b0 = rem ? kb + __builtin_ctzll(rem) : 512; rem &= rem - 1;
                    int b1 = rem ? kb + __builtin_ctzll(rem) : 512; rem &= rem - 1;
                    float4 w0 = *(const float4*)&Wsh[b0][hq4];
                    float4 w1 = *(const float4*)&Wsh[b1][hq4];
                    for (int i = 1; i < nit; ++i) {
                        int c0 = rem ? kb + __builtin_ctzll(rem) : 512; rem &= rem - 1;
                        int c1 = rem ? kb + __builtin_ctzll(rem) : 512; rem &= rem - 1;
                        float4 u0 = *(const float4*)&Wsh[c0][hq4];
                        float4 u1 = *(const float4*)&Wsh[c1][hq4];
                        acc.x += w0.x; acc.y += w0.y; acc.z += w0.z; acc.w += w0.w;
                        acc.x += w1.x; acc.y += w1.y; acc.z += w1.z; acc.w += w1.w;
                        w0 = u0; w1 = u1;
                    }
                    acc.x += w0.x; acc.y += w0.y; acc.z += w0.z; acc.w += w0.w;
                    acc.x += w1.x; acc.y += w1.y; acc.z += w1.z; acc.w += w1.w;
                }
                // LIF (same expression shape as prior exact rounds)
                float4 mnew;
                { float inp = acc.x + bfc.x; float mp = mem_fc.x;
                  float reset = (mp > 1.0f) ? 1.0f : 0.0f; mnew.x = 0.9f * mp + inp - reset; }
                { float inp = acc.y + bfc.y; float mp = mem_fc.y;
                  float reset = (mp > 1.0f) ? 1.0f : 0.0f; mnew.y = 0.9f * mp + inp - reset; }
                { float inp = acc.z + bfc.z; float mp = mem_fc.z;
                  float reset = (mp > 1.0f) ? 1.0f : 0.0f; mnew.z = 0.9f * mp + inp - reset; }
                { float inp = acc.w + bfc.w; float mp = mem_fc.w;
                  float reset = (mp > 1.0f) ? 1.0f : 0.0f; mnew.w = 0.9f * mp + inp - reset; }
                mem_fc = mnew;

                if (layer < 3) {
                    // ballot-pack: word bit(4*hq+j) = spike(row nl, h=h0+4hq+j)
                    u64 B0 = __ballot(mnew.x > 1.0f);
                    u64 B1 = __ballot(mnew.y > 1.0f);
                    u64 B2 = __ballot(mnew.z > 1.0f);
                    u64 B3 = __ballot(mnew.w > 1.0f);
                    const int sh = ng << 4;
                    u64 word = spread4((unsigned int)(B0 >> sh))
                             | (spread4((unsigned int)(B1 >> sh)) << 1)
                             | (spread4((unsigned int)(B2 >> sh)) << 2)
                             | (spread4((unsigned int)(B3 >> sh)) << 3);
                    if (hq == 0)
                        __hip_atomic_store(mdst + ((size_t)tt * NB + n0 + nl) * 8 + hs, word,
                                           __ATOMIC_RELAXED, __HIP_MEMORY_SCOPE_AGENT);
                } else {
                    float4 s4;
                    s4.x = (mnew.x > 1.0f) ? 1.0f : 0.0f;
                    s4.y = (mnew.y > 1.0f) ? 1.0f : 0.0f;
                    s4.z = (mnew.z > 1.0f) ? 1.0f : 0.0f;
                    s4.w = (mnew.w > 1.0f) ? 1.0f : 0.0f;
                    *(float4*)(outp + (size_t)tt * PLANE + (size_t)(n0 + nl) * H + h0 + hq4) = s4;
                }
            }
        }

        // ---- hierarchical store-based grid barrier ----
        asm volatile("s_waitcnt vmcnt(0)" ::: "memory");
        __syncthreads();
        if (tid == 0) {
            const int target = p + 1;
            __hip_atomic_store(slots + grp * 32 + gidx, target,
                               __ATOMIC_RELAXED, __HIP_MEMORY_SCOPE_AGENT);
            if (gidx == 0) {
                for (;;) {
                    int all = 1;
                    #pragma unroll
                    for (int i = 0; i < 32; ++i) {
                        int v = __hip_atomic_load(slots + grp * 32 + i,
                                                  __ATOMIC_RELAXED, __HIP_MEMORY_SCOPE_AGENT);
                        all &= (v >= target);
                    }
                    if (all) break;
                }
                __hip_atomic_store(done + grp, target,
                                   __ATOMIC_RELAXED, __HIP_MEMORY_SCOPE_AGENT);
                for (;;) {
                    int all = 1;
                    #pragma unroll
                    for (int i = 0; i < 8; ++i) {
                        int v = __hip_atomic_load(done + i,
                                                  __ATOMIC_RELAXED, __HIP_MEMORY_SCOPE_AGENT);
                        all &= (v >= target);
                    }
                    if (all) break;
                }
                __hip_atomic_store(rel + grp * 32, target,
                                   __ATOMIC_RELAXED, __HIP_MEMORY_SCOPE_AGENT);
            } else {
                while (__hip_atomic_load(rel + grp * 32,
                                         __ATOMIC_RELAXED, __HIP_MEMORY_SCOPE_AGENT) < target)
                    __builtin_amdgcn_s_sleep(1);
            }
        }
        __syncthreads();
    }

    // ---------- final membrane state ----------
    float* outm = out + (size_t)LSTEPS * PLANE;
    if (wave < 4)
        *(float2*)(outm + (size_t)en * H + eh) = mem_e;
    *(float4*)(outm + (size_t)(layer + 1) * PLANE + (size_t)(n0 + nl) * H + h0 + hq4) = mem_fc;
}

extern "C" void kernel_launch(void* const* d_in, const int* in_sizes, int n_in,
                              void* d_out, int out_size, void* d_ws, size_t ws_size,
                              hipStream_t stream) {
    const float* x     = (const float*)d_in[0];
    const float* mem0  = (const float*)d_in[1];
    const float* enc_W = (const float*)d_in[2];
    const float* enc_b = (const float*)d_in[3];
    const float* fc_W  = (const float*)d_in[4];
    const float* fc_b  = (const float*)d_in[5];
    float* out = (float*)d_out;

    float* fc_Wt  = (float*)d_ws;                     // 4 MB
    float* enc_Wt = fc_Wt + 4 * H * H;                // 256 KB
    u64*   masks  = (u64*)(enc_Wt + OBS * H);         // 8 planes * TB*256*8 u64 = 1 MB
    int*   bar    = (int*)(masks + 8 * PLSZ);         // slots 256 | done 32 | rel 256

    hipMemsetAsync(bar, 0, 544 * sizeof(int), stream);
    prep_weights<<<dim3(512), dim3(256), 0, stream>>>(enc_W, fc_W, enc_Wt, fc_Wt);
    snn_persistent<<<dim3(NWG), dim3(NTHR), 0, stream>>>(
        x, mem0, enc_b, fc_b, enc_Wt, fc_Wt, masks, bar, out);
}